// Round 5
// baseline (298.090 us; speedup 1.0000x reference)
//
#include <hip/hip_runtime.h>
#include <math.h>

#define NEG 0.2f

typedef __attribute__((ext_vector_type(8))) short bf16x8;
typedef __attribute__((ext_vector_type(4))) float f32x4;

__device__ __forceinline__ float lrelu(float x){ return x > 0.f ? x : NEG*x; }

__device__ __forceinline__ float bflo(unsigned u){ return __uint_as_float(u << 16); }
__device__ __forceinline__ float bfhi(unsigned u){ return __uint_as_float(u & 0xffff0000u); }

// select a0..a3 by 2-bit index encoded as booleans (bit0, bit1)
__device__ __forceinline__ float selh(float a0, float a1, float a2, float a3,
                                      bool bit0, bool bit1){
  float lo = bit0 ? a1 : a0;
  float hi = bit0 ? a3 : a2;
  return bit1 ? hi : lo;
}

__device__ __forceinline__ unsigned short f2bf(float x){
  unsigned u = __float_as_uint(x);
  u += 0x7fffu + ((u >> 16) & 1u);     // RNE
  return (unsigned short)(u >> 16);
}

// ---- detect whether edge_index is int64 (odd 32-bit words all zero) or int32 ----
__global__ void detect_kernel(const int* __restrict__ ei, int* __restrict__ flag){
  int lane = threadIdx.x;                 // 64 threads, 1 block
  int v = ei[2*lane + 1];
  unsigned long long b = __ballot(v != 0);
  if (lane == 0) flag[0] = (b == 0ULL) ? 1 : 0;   // 1 => int64 layout
}

__global__ void count_kernel(const int* __restrict__ ei, const int* __restrict__ flag,
                             int* __restrict__ counts, int E){
  int is64 = flag[0];
  int stride = gridDim.x * blockDim.x;
  for (int i = blockIdx.x*blockDim.x + threadIdx.x; i < E; i += stride){
    int d = is64 ? ei[2*(E + i)] : ei[E + i];
    atomicAdd(&counts[d], 1);
  }
}

// ---- parallel segment assignment: no ordered prefix sum needed for CSR ----
__global__ void assign_kernel(const int* __restrict__ counts, int* __restrict__ beg,
                              int* __restrict__ cursor, int* __restrict__ totalCtr, int n){
  int i = blockIdx.x*blockDim.x + threadIdx.x;
  if (i < n){
    int c = counts[i];
    int b = atomicAdd(totalCtr, c);
    beg[i] = b;
    cursor[i] = b;
  }
}

__global__ void fill_kernel(const int* __restrict__ ei, const int* __restrict__ flag,
                            int* __restrict__ cursor, int* __restrict__ adj, int E){
  int is64 = flag[0];
  int stride = gridDim.x * blockDim.x;
  for (int i = blockIdx.x*blockDim.x + threadIdx.x; i < E; i += stride){
    int s = is64 ? ei[2*i]       : ei[i];
    int d = is64 ? ei[2*(E + i)] : ei[E + i];
    int pos = atomicAdd(&cursor[d], 1);
    adj[pos] = s;
  }
}

// ---- GEMM1 via MFMA: h1b = bf16(x @ W1)  [N,128]x[128,256] ----
__device__ __forceinline__ int wt_addr(int col, int k){   // address in shorts
  int g = (k >> 3) ^ (col & 7);
  return col*128 + g*8 + (k & 7);
}

__global__ __launch_bounds__(256) void gemm1_mfma(const float* __restrict__ x,
                             const float* __restrict__ W,
                             unsigned short* __restrict__ h1b, int N){
  __shared__ unsigned short wt[256*128];   // 65536 B
  int t = threadIdx.x;
  int lane = t & 63, w = t >> 6;
  int row0 = blockIdx.x * 64 + w * 16;

  // A-frags from x: row = lane&15, k = (lane>>4)*8 + j
  int arow = row0 + (lane & 15);
  if (arow >= N) arow = N - 1;
  const float* xr = x + (size_t)arow * 128 + (lane >> 4) * 8;
  bf16x8 afrag[4];
  #pragma unroll
  for (int kk = 0; kk < 4; kk++){
    float4 p0 = *reinterpret_cast<const float4*>(xr + kk*32);
    float4 p1 = *reinterpret_cast<const float4*>(xr + kk*32 + 4);
    afrag[kk][0] = (short)f2bf(p0.x); afrag[kk][1] = (short)f2bf(p0.y);
    afrag[kk][2] = (short)f2bf(p0.z); afrag[kk][3] = (short)f2bf(p0.w);
    afrag[kk][4] = (short)f2bf(p1.x); afrag[kk][5] = (short)f2bf(p1.y);
    afrag[kk][6] = (short)f2bf(p1.z); afrag[kk][7] = (short)f2bf(p1.w);
  }

  // stage W1 transposed: thread t owns col c=t; coalesced global reads
  int c = t;
  for (int k0 = 0; k0 < 128; k0 += 8){
    bf16x8 v;
    #pragma unroll
    for (int j = 0; j < 8; j++) v[j] = (short)f2bf(W[(size_t)(k0+j)*256 + c]);
    *reinterpret_cast<bf16x8*>(&wt[wt_addr(c, k0)]) = v;
  }
  __syncthreads();

  f32x4 acc[16];
  #pragma unroll
  for (int n = 0; n < 16; n++) acc[n] = (f32x4){0.f,0.f,0.f,0.f};
  #pragma unroll
  for (int kk = 0; kk < 4; kk++){
    #pragma unroll
    for (int n = 0; n < 16; n++){
      bf16x8 b = *reinterpret_cast<const bf16x8*>(
          &wt[wt_addr(n*16 + (lane & 15), kk*32 + (lane >> 4)*8)]);
      acc[n] = __builtin_amdgcn_mfma_f32_16x16x32_bf16(afrag[kk], b, acc[n], 0, 0, 0);
    }
  }

  int rbase = row0 + (lane >> 4)*4;
  int cbase = lane & 15;
  #pragma unroll
  for (int n = 0; n < 16; n++){
    #pragma unroll
    for (int r = 0; r < 4; r++){
      int row = rbase + r;
      if (row < N) h1b[(size_t)row*256 + n*16 + cbase] = f2bf(acc[n][r]);
    }
  }
}

// ---- alpha1: as1/ad1[node][head] = sum_ch h1[node][head*64+ch] * a[head][ch] ----
__global__ void alpha1_kernel(const unsigned short* __restrict__ h1b,
                              const float* __restrict__ asrc, const float* __restrict__ adst,
                              float* __restrict__ as1, float* __restrict__ ad1, int N){
  int node = (blockIdx.x*blockDim.x + threadIdx.x) >> 6;
  int lane = threadIdx.x & 63;
  if (node >= N) return;
  uint2 hv = *reinterpret_cast<const uint2*>(h1b + (size_t)node*256 + lane*4);
  float h0 = bflo(hv.x), h1 = bfhi(hv.x), h2 = bflo(hv.y), h3 = bfhi(hv.y);
  int head = lane >> 4, ch = (lane & 15)*4;
  float4 av = *reinterpret_cast<const float4*>(asrc + head*64 + ch);
  float4 dv = *reinterpret_cast<const float4*>(adst + head*64 + ch);
  float ps = h0*av.x + h1*av.y + h2*av.z + h3*av.w;
  float pd = h0*dv.x + h1*dv.y + h2*dv.z + h3*dv.w;
  #pragma unroll
  for (int off = 1; off < 16; off <<= 1){
    ps += __shfl_xor(ps, off, 64);
    pd += __shfl_xor(pd, off, 64);
  }
  if ((lane & 15) == 0){
    as1[node*4 + head] = ps;
    ad1[node*4 + head] = pd;
  }
}

// ---- layer-1 aggregation: wave per dst node, online softmax.
//      Quad-edge broadcast: 16 lanes/edge, 16 ch/lane (32B), weights via LDS. ----
__global__ void agg1_kernel(const unsigned short* __restrict__ h1b,
                            const float* __restrict__ as1,
                            const float* __restrict__ ad1, const float* __restrict__ b1,
                            const int* __restrict__ beg, const int* __restrict__ counts,
                            const int* __restrict__ adj,
                            float* __restrict__ hact, int N){
  __shared__ float exlds[4][256];
  __shared__ int   srclds[4][64];
  int node = (blockIdx.x*blockDim.x + threadIdx.x) >> 6;
  int lane = threadIdx.x & 63;
  int w = (threadIdx.x >> 6) & 3;
  if (node >= N) return;
  int beg_ = beg[node], end_ = beg_ + counts[node];
  int hl = lane & 15;            // channel-group: channels hl*16 .. hl*16+15
  int quarter = lane >> 4;       // which edge of the quad this lane serves
  int hh = hl >> 2;              // head of this lane's channels
  bool c4 = (hl & 4) != 0, c8 = (hl & 8) != 0;   // hh bits for selh

  float4 adv4 = *reinterpret_cast<const float4*>(ad1 + (size_t)node*4);
  float adv[4] = {adv4.x, adv4.y, adv4.z, adv4.w};
  float4 sv4 = *reinterpret_cast<const float4*>(as1 + (size_t)node*4);
  float svv[4] = {sv4.x, sv4.y, sv4.z, sv4.w};

  float es[4], m[4], sp[4];
  #pragma unroll
  for (int k = 0; k < 4; k++){
    es[k] = lrelu(svv[k] + adv[k]);   // self-loop logit
    m[k] = es[k];
    sp[k] = 0.f;
  }
  float acc[16];
  #pragma unroll
  for (int c = 0; c < 16; c++) acc[c] = 0.f;

  for (int base = beg_; base < end_; base += 64){
    int i = base + lane;
    bool val = i < end_;
    int srcl = val ? adj[i] : 0;
    float4 av4 = *reinterpret_cast<const float4*>(as1 + (size_t)srcl*4);
    float e[4] = {av4.x, av4.y, av4.z, av4.w};
    #pragma unroll
    for (int k = 0; k < 4; k++) e[k] = val ? lrelu(e[k] + adv[k]) : -3e38f;

    // chunk max + online rescale
    float sc[4];
    #pragma unroll
    for (int k = 0; k < 4; k++){
      float cm = e[k];
      #pragma unroll
      for (int off = 32; off; off >>= 1) cm = fmaxf(cm, __shfl_xor(cm, off, 64));
      float nm = fmaxf(m[k], cm);
      sc[k] = __expf(m[k] - nm);
      m[k] = nm;
      sp[k] *= sc[k];
    }
    float sch = selh(sc[0], sc[1], sc[2], sc[3], c4, c8);
    #pragma unroll
    for (int c = 0; c < 16; c++) acc[c] *= sch;

    // per-edge exp once (lane-parallel over edges); stash to LDS
    float ex[4];
    #pragma unroll
    for (int k = 0; k < 4; k++){
      ex[k] = __expf(e[k] - m[k]);    // invalid lanes -> 0
      sp[k] += ex[k];
    }
    *reinterpret_cast<float4*>(&exlds[w][lane*4]) = make_float4(ex[0], ex[1], ex[2], ex[3]);
    srclds[w][lane] = srcl;

    // quad-edge broadcast: 4 edges/iter, 16 lanes each, 16 ch (32 B) per lane
    int cnt = end_ - base; if (cnt > 64) cnt = 64;
    #pragma unroll 2
    for (int j = 0; j < cnt; j += 4){
      int j0 = j + quarter;
      int src = srclds[w][j0];
      float eh = exlds[w][j0*4 + hh];
      const unsigned short* hr = h1b + (size_t)src*256 + hl*16;
      uint4 ha = *reinterpret_cast<const uint4*>(hr);
      uint4 hb = *reinterpret_cast<const uint4*>(hr + 8);
      acc[ 0] = fmaf(eh, bflo(ha.x), acc[ 0]);
      acc[ 1] = fmaf(eh, bfhi(ha.x), acc[ 1]);
      acc[ 2] = fmaf(eh, bflo(ha.y), acc[ 2]);
      acc[ 3] = fmaf(eh, bfhi(ha.y), acc[ 3]);
      acc[ 4] = fmaf(eh, bflo(ha.z), acc[ 4]);
      acc[ 5] = fmaf(eh, bfhi(ha.z), acc[ 5]);
      acc[ 6] = fmaf(eh, bflo(ha.w), acc[ 6]);
      acc[ 7] = fmaf(eh, bfhi(ha.w), acc[ 7]);
      acc[ 8] = fmaf(eh, bflo(hb.x), acc[ 8]);
      acc[ 9] = fmaf(eh, bfhi(hb.x), acc[ 9]);
      acc[10] = fmaf(eh, bflo(hb.y), acc[10]);
      acc[11] = fmaf(eh, bfhi(hb.y), acc[11]);
      acc[12] = fmaf(eh, bflo(hb.z), acc[12]);
      acc[13] = fmaf(eh, bfhi(hb.z), acc[13]);
      acc[14] = fmaf(eh, bflo(hb.w), acc[14]);
      acc[15] = fmaf(eh, bfhi(hb.w), acc[15]);
    }
  }

  // denominator per head (wave-total) + self-loop exp
  #pragma unroll
  for (int k = 0; k < 4; k++){
    #pragma unroll
    for (int off = 32; off; off >>= 1) sp[k] += __shfl_xor(sp[k], off, 64);
  }
  float exs[4];
  #pragma unroll
  for (int k = 0; k < 4; k++){
    exs[k] = __expf(es[k] - m[k]);
    sp[k] += exs[k];
  }

  // combine quarter-partials: lanes {L, L+16, L+32, L+48} hold same channels
  #pragma unroll
  for (int c = 0; c < 16; c++){
    acc[c] += __shfl_xor(acc[c], 16, 64);
    acc[c] += __shfl_xor(acc[c], 32, 64);
  }

  if (quarter == 0){   // lanes 0..15 finalize + store their 16 channels
    float ehs = selh(exs[0], exs[1], exs[2], exs[3], c4, c8);
    const unsigned short* hr = h1b + (size_t)node*256 + hl*16;
    uint4 ha = *reinterpret_cast<const uint4*>(hr);
    uint4 hb = *reinterpret_cast<const uint4*>(hr + 8);
    acc[ 0] = fmaf(ehs, bflo(ha.x), acc[ 0]);
    acc[ 1] = fmaf(ehs, bfhi(ha.x), acc[ 1]);
    acc[ 2] = fmaf(ehs, bflo(ha.y), acc[ 2]);
    acc[ 3] = fmaf(ehs, bfhi(ha.y), acc[ 3]);
    acc[ 4] = fmaf(ehs, bflo(ha.z), acc[ 4]);
    acc[ 5] = fmaf(ehs, bfhi(ha.z), acc[ 5]);
    acc[ 6] = fmaf(ehs, bflo(ha.w), acc[ 6]);
    acc[ 7] = fmaf(ehs, bfhi(ha.w), acc[ 7]);
    acc[ 8] = fmaf(ehs, bflo(hb.x), acc[ 8]);
    acc[ 9] = fmaf(ehs, bfhi(hb.x), acc[ 9]);
    acc[10] = fmaf(ehs, bflo(hb.y), acc[10]);
    acc[11] = fmaf(ehs, bfhi(hb.y), acc[11]);
    acc[12] = fmaf(ehs, bflo(hb.z), acc[12]);
    acc[13] = fmaf(ehs, bfhi(hb.z), acc[13]);
    acc[14] = fmaf(ehs, bflo(hb.w), acc[14]);
    acc[15] = fmaf(ehs, bfhi(hb.w), acc[15]);

    float rinv = 1.0f / (selh(sp[0], sp[1], sp[2], sp[3], c4, c8) + 1e-16f);
    float o[16];
    #pragma unroll
    for (int q = 0; q < 4; q++){
      float4 bv = *reinterpret_cast<const float4*>(b1 + hl*16 + q*4);
      o[q*4+0] = acc[q*4+0]*rinv + bv.x;
      o[q*4+1] = acc[q*4+1]*rinv + bv.y;
      o[q*4+2] = acc[q*4+2]*rinv + bv.z;
      o[q*4+3] = acc[q*4+3]*rinv + bv.w;
    }
    #pragma unroll
    for (int c = 0; c < 16; c++) o[c] = o[c] > 0.f ? o[c] : expm1f(o[c]);
    float* orow = hact + (size_t)node*256 + hl*16;
    #pragma unroll
    for (int q = 0; q < 4; q++)
      *reinterpret_cast<float4*>(orow + q*4) =
          make_float4(o[q*4+0], o[q*4+1], o[q*4+2], o[q*4+3]);
  }
}

// ---- GEMM2: h2 = hact @ W2  [N,256]x[256,16], fused alpha_src2/alpha_dst2 ----
__global__ void gemm2_kernel(const float* __restrict__ hact, const float* __restrict__ W2,
                             const float* __restrict__ asrc, const float* __restrict__ adst,
                             float* __restrict__ h2, float* __restrict__ as2,
                             float* __restrict__ ad2){
  __shared__ float a_s[16][260];
  __shared__ float w_s[256*16];
  int t = threadIdx.x;
  int row0 = blockIdx.x * 16;
  for (int i = t; i < 1024; i += 256)
    reinterpret_cast<float4*>(w_s)[i] = reinterpret_cast<const float4*>(W2)[i];
  const float4* hv = reinterpret_cast<const float4*>(hact + (size_t)row0 * 256);
  for (int i = t; i < 1024; i += 256){
    int r = i >> 6, j = i & 63;
    *reinterpret_cast<float4*>(&a_s[r][j*4]) = hv[(size_t)r*64 + j];
  }
  __syncthreads();
  int r = t >> 4, c = t & 15;
  float acc = 0.f;
  #pragma unroll 4
  for (int k = 0; k < 256; k++) acc = fmaf(a_s[r][k], w_s[k*16 + c], acc);
  int node = row0 + r;
  h2[(size_t)node*16 + c] = acc;
  float ps = acc * asrc[c], pd = acc * adst[c];
  #pragma unroll
  for (int off = 1; off < 16; off <<= 1){
    ps += __shfl_xor(ps, off, 64);
    pd += __shfl_xor(pd, off, 64);
  }
  if (c == 0){ as2[node] = ps; ad2[node] = pd; }
}

// ---- layer-2 aggregation: wave per node (4 edge-groups x 16 channels), fused bias+log_softmax ----
__global__ void agg2_kernel(const float* __restrict__ h2, const float* __restrict__ as2,
                            const float* __restrict__ ad2, const float* __restrict__ b2,
                            const int* __restrict__ beg, const int* __restrict__ counts,
                            const int* __restrict__ adj,
                            float* __restrict__ out, int N){
  int node = (blockIdx.x*blockDim.x + threadIdx.x) >> 6;
  int lane = threadIdx.x & 63;
  if (node >= N) return;
  int beg_ = beg[node], end_ = beg_ + counts[node];
  float adn = ad2[node];
  float m = -1e30f;
  for (int i = beg_ + lane; i < end_; i += 64)
    m = fmaxf(m, lrelu(as2[adj[i]] + adn));
  float eself = lrelu(as2[node] + adn);
  m = fmaxf(m, eself);
  #pragma unroll
  for (int off = 32; off; off >>= 1) m = fmaxf(m, __shfl_xor(m, off, 64));
  int g = lane >> 4, c = lane & 15;
  float s = 0.f, acc = 0.f;
  for (int i = beg_ + g; i < end_; i += 4){
    int src = adj[i];
    float ex = __expf(lrelu(as2[src] + adn) - m);
    s += ex;
    acc = fmaf(ex, h2[(size_t)src*16 + c], acc);
  }
  if (g == 0){
    float ex = __expf(eself - m);
    s += ex;
    acc = fmaf(ex, h2[(size_t)node*16 + c], acc);
  }
  acc += __shfl_xor(acc, 16, 64); acc += __shfl_xor(acc, 32, 64);
  s   += __shfl_xor(s,   16, 64); s   += __shfl_xor(s,   32, 64);
  float v = acc / (s + 1e-16f) + b2[c];
  float mx = v;
  #pragma unroll
  for (int off = 1; off < 16; off <<= 1) mx = fmaxf(mx, __shfl_xor(mx, off, 64));
  float se = expf(v - mx);
  #pragma unroll
  for (int off = 1; off < 16; off <<= 1) se += __shfl_xor(se, off, 64);
  float o = v - mx - logf(se);
  if (lane < 16) out[(size_t)node*16 + c] = o;
}

extern "C" void kernel_launch(void* const* d_in, const int* in_sizes, int n_in,
                              void* d_out, int out_size, void* d_ws, size_t ws_size,
                              hipStream_t stream){
  const float* x    = (const float*)d_in[0];
  const int*   ei   = (const int*)d_in[1];
  const float* W1   = (const float*)d_in[2];
  const float* as1w = (const float*)d_in[3];
  const float* ad1w = (const float*)d_in[4];
  const float* b1   = (const float*)d_in[5];
  const float* W2   = (const float*)d_in[6];
  const float* as2w = (const float*)d_in[7];
  const float* ad2w = (const float*)d_in[8];
  const float* b2   = (const float*)d_in[9];
  float* out = (float*)d_out;

  int N = in_sizes[0] / 128;   // 50000
  int E = in_sizes[1] / 2;     // 800000

  char* p = (char*)d_ws;
  size_t off = 0;
  auto alloc = [&](size_t b){ size_t c = off; off = (off + b + 255) & ~(size_t)255; return c; };
  unsigned short* h1b = (unsigned short*)(p + alloc((size_t)N*256*2)); // 25.6 MB bf16
  float* hact   = (float*)(p + alloc((size_t)N*256*4));   // 51.2 MB
  float* h2     = (float*)(p + alloc((size_t)N*16*4));    // 3.2 MB
  float* as1    = (float*)(p + alloc((size_t)N*4*4));
  float* ad1    = (float*)(p + alloc((size_t)N*4*4));
  float* as2    = (float*)(p + alloc((size_t)N*4));
  float* ad2    = (float*)(p + alloc((size_t)N*4));
  int*   counts = (int*)(p + alloc((size_t)N*4));
  int*   beg    = (int*)(p + alloc((size_t)N*4));
  int*   cursor = (int*)(p + alloc((size_t)N*4));
  int*   adj    = (int*)(p + alloc((size_t)E*4));         // 3.2 MB
  int*   flag   = (int*)(p + alloc(4));
  int*   totalCtr = (int*)(p + alloc(4));

  hipMemsetAsync(counts, 0, (size_t)N*4, stream);
  hipMemsetAsync(totalCtr, 0, 4, stream);
  detect_kernel<<<1, 64, 0, stream>>>(ei, flag);
  count_kernel<<<2048, 256, 0, stream>>>(ei, flag, counts, E);
  assign_kernel<<<(N + 255)/256, 256, 0, stream>>>(counts, beg, cursor, totalCtr, N);
  fill_kernel<<<2048, 256, 0, stream>>>(ei, flag, cursor, adj, E);

  gemm1_mfma<<<(N + 63)/64, 256, 0, stream>>>(x, W1, h1b, N);
  alpha1_kernel<<<(N*64 + 255)/256, 256, 0, stream>>>(h1b, as1w, ad1w, as1, ad1, N);
  agg1_kernel<<<(N*64 + 255)/256, 256, 0, stream>>>(h1b, as1, ad1, b1, beg, counts, adj, hact, N);
  gemm2_kernel<<<N/16, 256, 0, stream>>>(hact, W2, as2w, ad2w, h2, as2, ad2);
  agg2_kernel<<<(N*64 + 255)/256, 256, 0, stream>>>(h2, as2, ad2, b2, beg, counts, adj, out, N);
}

// Round 6
// 269.410 us; speedup vs baseline: 1.1065x; 1.1065x over previous
//
#include <hip/hip_runtime.h>
#include <math.h>

#define NEG 0.2f

typedef __attribute__((ext_vector_type(8))) short bf16x8;
typedef __attribute__((ext_vector_type(4))) float f32x4;

__device__ __forceinline__ float lrelu(float x){ return x > 0.f ? x : NEG*x; }

__device__ __forceinline__ float bflo(unsigned u){ return __uint_as_float(u << 16); }
__device__ __forceinline__ float bfhi(unsigned u){ return __uint_as_float(u & 0xffff0000u); }

__device__ __forceinline__ float rl(float x, int j){
  return __uint_as_float((unsigned)__builtin_amdgcn_readlane((int)__float_as_uint(x), j));
}

// select a0..a3 by 2-bit index encoded as booleans (bit0, bit1)
__device__ __forceinline__ float selh(float a0, float a1, float a2, float a3,
                                      bool bit0, bool bit1){
  float lo = bit0 ? a1 : a0;
  float hi = bit0 ? a3 : a2;
  return bit1 ? hi : lo;
}

__device__ __forceinline__ unsigned short f2bf(float x){
  unsigned u = __float_as_uint(x);
  u += 0x7fffu + ((u >> 16) & 1u);     // RNE
  return (unsigned short)(u >> 16);
}

// ---- detect whether edge_index is int64 (odd 32-bit words all zero) or int32 ----
__global__ void detect_kernel(const int* __restrict__ ei, int* __restrict__ flag){
  int lane = threadIdx.x;                 // 64 threads, 1 block
  int v = ei[2*lane + 1];
  unsigned long long b = __ballot(v != 0);
  if (lane == 0) flag[0] = (b == 0ULL) ? 1 : 0;   // 1 => int64 layout
}

__global__ void count_kernel(const int* __restrict__ ei, const int* __restrict__ flag,
                             int* __restrict__ counts, int E){
  int is64 = flag[0];
  int stride = gridDim.x * blockDim.x;
  for (int i = blockIdx.x*blockDim.x + threadIdx.x; i < E; i += stride){
    int d = is64 ? ei[2*(E + i)] : ei[E + i];
    atomicAdd(&counts[d], 1);
  }
}

// ---- parallel segment assignment: no ordered prefix sum needed for CSR ----
__global__ void assign_kernel(const int* __restrict__ counts, int* __restrict__ beg,
                              int* __restrict__ cursor, int* __restrict__ totalCtr, int n){
  int i = blockIdx.x*blockDim.x + threadIdx.x;
  if (i < n){
    int c = counts[i];
    int b = atomicAdd(totalCtr, c);
    beg[i] = b;
    cursor[i] = b;
  }
}

__global__ void fill_kernel(const int* __restrict__ ei, const int* __restrict__ flag,
                            int* __restrict__ cursor, int* __restrict__ adj, int E){
  int is64 = flag[0];
  int stride = gridDim.x * blockDim.x;
  for (int i = blockIdx.x*blockDim.x + threadIdx.x; i < E; i += stride){
    int s = is64 ? ei[2*i]       : ei[i];
    int d = is64 ? ei[2*(E + i)] : ei[E + i];
    int pos = atomicAdd(&cursor[d], 1);
    adj[pos] = s;
  }
}

// ---- GEMM1 via MFMA: h1b = bf16(x @ W1)  [N,128]x[128,256], fused alpha1 ----
__device__ __forceinline__ int wt_addr(int col, int k){   // address in shorts, K=128
  int g = (k >> 3) ^ (col & 7);
  return col*128 + g*8 + (k & 7);
}

__global__ __launch_bounds__(256) void gemm1_mfma(const float* __restrict__ x,
                             const float* __restrict__ W,
                             const float* __restrict__ asrcw, const float* __restrict__ adstw,
                             unsigned short* __restrict__ h1b,
                             float* __restrict__ as1, float* __restrict__ ad1, int N){
  __shared__ unsigned short wt[256*128];   // 65536 B
  int t = threadIdx.x;
  int lane = t & 63, w = t >> 6;
  int row0 = blockIdx.x * 64 + w * 16;

  // A-frags from x: row = lane&15, k = (lane>>4)*8 + j
  int arow = row0 + (lane & 15);
  if (arow >= N) arow = N - 1;
  const float* xr = x + (size_t)arow * 128 + (lane >> 4) * 8;
  bf16x8 afrag[4];
  #pragma unroll
  for (int kk = 0; kk < 4; kk++){
    float4 p0 = *reinterpret_cast<const float4*>(xr + kk*32);
    float4 p1 = *reinterpret_cast<const float4*>(xr + kk*32 + 4);
    afrag[kk][0] = (short)f2bf(p0.x); afrag[kk][1] = (short)f2bf(p0.y);
    afrag[kk][2] = (short)f2bf(p0.z); afrag[kk][3] = (short)f2bf(p0.w);
    afrag[kk][4] = (short)f2bf(p1.x); afrag[kk][5] = (short)f2bf(p1.y);
    afrag[kk][6] = (short)f2bf(p1.z); afrag[kk][7] = (short)f2bf(p1.w);
  }

  // stage W1 transposed: thread t owns col c=t; coalesced global reads
  int c = t;
  for (int k0 = 0; k0 < 128; k0 += 8){
    bf16x8 v;
    #pragma unroll
    for (int j = 0; j < 8; j++) v[j] = (short)f2bf(W[(size_t)(k0+j)*256 + c]);
    *reinterpret_cast<bf16x8*>(&wt[wt_addr(c, k0)]) = v;
  }
  __syncthreads();

  f32x4 acc[16];
  #pragma unroll
  for (int n = 0; n < 16; n++) acc[n] = (f32x4){0.f,0.f,0.f,0.f};
  #pragma unroll
  for (int kk = 0; kk < 4; kk++){
    #pragma unroll
    for (int n = 0; n < 16; n++){
      bf16x8 b = *reinterpret_cast<const bf16x8*>(
          &wt[wt_addr(n*16 + (lane & 15), kk*32 + (lane >> 4)*8)]);
      acc[n] = __builtin_amdgcn_mfma_f32_16x16x32_bf16(afrag[kk], b, acc[n], 0, 0, 0);
    }
  }

  // store h1b: row = row0 + (lane>>4)*4 + r, col = n*16 + (lane&15)
  int rbase = row0 + (lane >> 4)*4;
  int cbase = lane & 15;
  #pragma unroll
  for (int n = 0; n < 16; n++){
    #pragma unroll
    for (int r = 0; r < 4; r++){
      int row = rbase + r;
      if (row < N) h1b[(size_t)row*256 + n*16 + cbase] = f2bf(acc[n][r]);
    }
  }

  // fused alpha1: per row r, per head h: sum over cols n in [4h,4h+4) of acc[n][r]*a[n*16+cbase]
  float av[16], dv[16];
  #pragma unroll
  for (int n = 0; n < 16; n++){
    av[n] = asrcw[n*16 + cbase];
    dv[n] = adstw[n*16 + cbase];
  }
  #pragma unroll
  for (int r = 0; r < 4; r++){
    int row = rbase + r;
    float hs[4], hd[4];
    #pragma unroll
    for (int h = 0; h < 4; h++){
      float ps = 0.f, pd = 0.f;
      #pragma unroll
      for (int q = 0; q < 4; q++){
        int n = h*4 + q;
        ps = fmaf(acc[n][r], av[n], ps);
        pd = fmaf(acc[n][r], dv[n], pd);
      }
      #pragma unroll
      for (int off = 1; off < 16; off <<= 1){
        ps += __shfl_xor(ps, off, 64);
        pd += __shfl_xor(pd, off, 64);
      }
      hs[h] = ps; hd[h] = pd;
    }
    if (cbase == 0 && row < N){
      *reinterpret_cast<float4*>(as1 + (size_t)row*4) = make_float4(hs[0],hs[1],hs[2],hs[3]);
      *reinterpret_cast<float4*>(ad1 + (size_t)row*4) = make_float4(hd[0],hd[1],hd[2],hd[3]);
    }
  }
}

// ---- layer-1 aggregation (R4 structure): wave per dst node, online softmax,
//      readlane broadcast, bf16 gather; fused bias+ELU; bf16 hact store ----
__global__ void agg1_kernel(const unsigned short* __restrict__ h1b,
                            const float* __restrict__ as1,
                            const float* __restrict__ ad1, const float* __restrict__ b1,
                            const int* __restrict__ beg, const int* __restrict__ counts,
                            const int* __restrict__ adj,
                            unsigned short* __restrict__ hact_b, int N){
  int node = (blockIdx.x*blockDim.x + threadIdx.x) >> 6;
  int lane = threadIdx.x & 63;
  if (node >= N) return;
  int beg_ = beg[node], end_ = beg_ + counts[node];
  bool b4 = (lane & 16) != 0, b5 = (lane & 32) != 0;   // head = lane>>4

  float4 adv4 = *reinterpret_cast<const float4*>(ad1 + (size_t)node*4);
  float adv[4] = {adv4.x, adv4.y, adv4.z, adv4.w};
  float4 sv4 = *reinterpret_cast<const float4*>(as1 + (size_t)node*4);
  float svv[4] = {sv4.x, sv4.y, sv4.z, sv4.w};

  float es[4], m[4], sp[4];
  #pragma unroll
  for (int k = 0; k < 4; k++){
    es[k] = lrelu(svv[k] + adv[k]);   // self-loop logit
    m[k] = es[k];
    sp[k] = 0.f;
  }
  float4 acc = make_float4(0.f, 0.f, 0.f, 0.f);

  for (int base = beg_; base < end_; base += 64){
    int i = base + lane;
    bool val = i < end_;
    int srcl = val ? adj[i] : 0;
    float4 av4 = *reinterpret_cast<const float4*>(as1 + (size_t)srcl*4);
    float e[4] = {av4.x, av4.y, av4.z, av4.w};
    #pragma unroll
    for (int k = 0; k < 4; k++) e[k] = val ? lrelu(e[k] + adv[k]) : -3e38f;

    // chunk max + online rescale
    float sc[4];
    #pragma unroll
    for (int k = 0; k < 4; k++){
      float cm = e[k];
      #pragma unroll
      for (int off = 32; off; off >>= 1) cm = fmaxf(cm, __shfl_xor(cm, off, 64));
      float nm = fmaxf(m[k], cm);
      sc[k] = __expf(m[k] - nm);
      m[k] = nm;
      sp[k] *= sc[k];
    }
    float sch = selh(sc[0], sc[1], sc[2], sc[3], b4, b5);
    acc.x *= sch; acc.y *= sch; acc.z *= sch; acc.w *= sch;

    // per-edge exp computed ONCE (lane-parallel over edges)
    float ex[4];
    #pragma unroll
    for (int k = 0; k < 4; k++){
      ex[k] = __expf(e[k] - m[k]);    // invalid lanes -> 0
      sp[k] += ex[k];
    }

    // broadcast phase: readlane weights, bf16x4 (uint2) gather of h1[src]
    int cnt = end_ - base; if (cnt > 64) cnt = 64;
    #pragma unroll 2
    for (int j = 0; j < cnt; j++){
      int srcj = __builtin_amdgcn_readlane(srcl, j);
      float e0 = rl(ex[0], j), e1 = rl(ex[1], j);
      float e2 = rl(ex[2], j), e3 = rl(ex[3], j);
      float eh = selh(e0, e1, e2, e3, b4, b5);
      uint2 hv = *reinterpret_cast<const uint2*>(h1b + (size_t)srcj*256 + lane*4);
      acc.x = fmaf(eh, bflo(hv.x), acc.x);
      acc.y = fmaf(eh, bfhi(hv.x), acc.y);
      acc.z = fmaf(eh, bflo(hv.y), acc.z);
      acc.w = fmaf(eh, bfhi(hv.y), acc.w);
    }
  }

  // total denominator per head
  #pragma unroll
  for (int k = 0; k < 4; k++){
    #pragma unroll
    for (int off = 32; off; off >>= 1) sp[k] += __shfl_xor(sp[k], off, 64);
  }
  // self-loop contribution
  float exs[4];
  #pragma unroll
  for (int k = 0; k < 4; k++){
    exs[k] = __expf(es[k] - m[k]);
    sp[k] += exs[k];
  }
  float ehs = selh(exs[0], exs[1], exs[2], exs[3], b4, b5);
  uint2 hv = *reinterpret_cast<const uint2*>(h1b + (size_t)node*256 + lane*4);
  acc.x = fmaf(ehs, bflo(hv.x), acc.x);
  acc.y = fmaf(ehs, bfhi(hv.x), acc.y);
  acc.z = fmaf(ehs, bflo(hv.y), acc.z);
  acc.w = fmaf(ehs, bfhi(hv.y), acc.w);

  float dh = selh(sp[0], sp[1], sp[2], sp[3], b4, b5) + 1e-16f;
  float rinv = 1.0f / dh;
  float4 bv = *reinterpret_cast<const float4*>(b1 + lane*4);
  float4 o;
  o.x = acc.x*rinv + bv.x;
  o.y = acc.y*rinv + bv.y;
  o.z = acc.z*rinv + bv.z;
  o.w = acc.w*rinv + bv.w;
  o.x = o.x > 0.f ? o.x : expm1f(o.x);
  o.y = o.y > 0.f ? o.y : expm1f(o.y);
  o.z = o.z > 0.f ? o.z : expm1f(o.z);
  o.w = o.w > 0.f ? o.w : expm1f(o.w);
  ushort4 ob;
  ob.x = f2bf(o.x); ob.y = f2bf(o.y); ob.z = f2bf(o.z); ob.w = f2bf(o.w);
  *reinterpret_cast<ushort4*>(hact_b + (size_t)node*256 + lane*4) = ob;
}

// ---- GEMM2 via MFMA: h2 = hact_b @ W2  [N,256]x[256,16], fused alpha2 ----
__device__ __forceinline__ int wt2_addr(int col, int k){  // shorts, K=256
  int g = (k >> 3) ^ (col & 7);
  return col*256 + g*8 + (k & 7);
}

__global__ __launch_bounds__(256) void gemm2_mfma(const unsigned short* __restrict__ hact_b,
                             const float* __restrict__ W2,
                             const float* __restrict__ asrc2, const float* __restrict__ adst2,
                             float* __restrict__ h2, float* __restrict__ as2,
                             float* __restrict__ ad2, int N){
  __shared__ unsigned short wt[16*256];    // 8192 B
  int t = threadIdx.x;
  int lane = t & 63, w = t >> 6;
  int row0 = blockIdx.x * 64 + w * 16;

  // stage W2^T bf16: thread t owns k=t (row of W2), writes 16 cols
  {
    float4 r0 = *reinterpret_cast<const float4*>(W2 + (size_t)t*16);
    float4 r1 = *reinterpret_cast<const float4*>(W2 + (size_t)t*16 + 4);
    float4 r2 = *reinterpret_cast<const float4*>(W2 + (size_t)t*16 + 8);
    float4 r3 = *reinterpret_cast<const float4*>(W2 + (size_t)t*16 + 12);
    float wr[16] = {r0.x,r0.y,r0.z,r0.w, r1.x,r1.y,r1.z,r1.w,
                    r2.x,r2.y,r2.z,r2.w, r3.x,r3.y,r3.z,r3.w};
    #pragma unroll
    for (int cc = 0; cc < 16; cc++) wt[wt2_addr(cc, t)] = f2bf(wr[cc]);
  }

  // A-frag source row
  int arow = row0 + (lane & 15);
  if (arow >= N) arow = N - 1;
  const unsigned short* hr = hact_b + (size_t)arow*256 + (lane >> 4)*8;
  __syncthreads();

  f32x4 acc = (f32x4){0.f,0.f,0.f,0.f};
  #pragma unroll
  for (int kk = 0; kk < 8; kk++){
    bf16x8 a = *reinterpret_cast<const bf16x8*>(hr + kk*32);
    bf16x8 b = *reinterpret_cast<const bf16x8*>(
        &wt[wt2_addr(lane & 15, kk*32 + (lane >> 4)*8)]);
    acc = __builtin_amdgcn_mfma_f32_16x16x32_bf16(a, b, acc, 0, 0, 0);
  }

  // store h2 + fused alpha2 (cols = lane&15, rows = row0 + (lane>>4)*4 + r)
  int rbase = row0 + (lane >> 4)*4;
  int cbase = lane & 15;
  float avc = asrc2[cbase], dvc = adst2[cbase];
  #pragma unroll
  for (int r = 0; r < 4; r++){
    int row = rbase + r;
    if (row < N) h2[(size_t)row*16 + cbase] = acc[r];
    float ps = acc[r]*avc, pd = acc[r]*dvc;
    #pragma unroll
    for (int off = 1; off < 16; off <<= 1){
      ps += __shfl_xor(ps, off, 64);
      pd += __shfl_xor(pd, off, 64);
    }
    if (cbase == 0 && row < N){ as2[row] = ps; ad2[row] = pd; }
  }
}

// ---- layer-2 aggregation: wave per node (4 edge-groups x 16 channels), fused bias+log_softmax ----
__global__ void agg2_kernel(const float* __restrict__ h2, const float* __restrict__ as2,
                            const float* __restrict__ ad2, const float* __restrict__ b2,
                            const int* __restrict__ beg, const int* __restrict__ counts,
                            const int* __restrict__ adj,
                            float* __restrict__ out, int N){
  int node = (blockIdx.x*blockDim.x + threadIdx.x) >> 6;
  int lane = threadIdx.x & 63;
  if (node >= N) return;
  int beg_ = beg[node], end_ = beg_ + counts[node];
  float adn = ad2[node];
  float m = -1e30f;
  for (int i = beg_ + lane; i < end_; i += 64)
    m = fmaxf(m, lrelu(as2[adj[i]] + adn));
  float eself = lrelu(as2[node] + adn);
  m = fmaxf(m, eself);
  #pragma unroll
  for (int off = 32; off; off >>= 1) m = fmaxf(m, __shfl_xor(m, off, 64));
  int g = lane >> 4, c = lane & 15;
  float s = 0.f, acc = 0.f;
  for (int i = beg_ + g; i < end_; i += 4){
    int src = adj[i];
    float ex = __expf(lrelu(as2[src] + adn) - m);
    s += ex;
    acc = fmaf(ex, h2[(size_t)src*16 + c], acc);
  }
  if (g == 0){
    float ex = __expf(eself - m);
    s += ex;
    acc = fmaf(ex, h2[(size_t)node*16 + c], acc);
  }
  acc += __shfl_xor(acc, 16, 64); acc += __shfl_xor(acc, 32, 64);
  s   += __shfl_xor(s,   16, 64); s   += __shfl_xor(s,   32, 64);
  float v = acc / (s + 1e-16f) + b2[c];
  float mx = v;
  #pragma unroll
  for (int off = 1; off < 16; off <<= 1) mx = fmaxf(mx, __shfl_xor(mx, off, 64));
  float se = expf(v - mx);
  #pragma unroll
  for (int off = 1; off < 16; off <<= 1) se += __shfl_xor(se, off, 64);
  float o = v - mx - logf(se);
  if (lane < 16) out[(size_t)node*16 + c] = o;
}

extern "C" void kernel_launch(void* const* d_in, const int* in_sizes, int n_in,
                              void* d_out, int out_size, void* d_ws, size_t ws_size,
                              hipStream_t stream){
  const float* x    = (const float*)d_in[0];
  const int*   ei   = (const int*)d_in[1];
  const float* W1   = (const float*)d_in[2];
  const float* as1w = (const float*)d_in[3];
  const float* ad1w = (const float*)d_in[4];
  const float* b1   = (const float*)d_in[5];
  const float* W2   = (const float*)d_in[6];
  const float* as2w = (const float*)d_in[7];
  const float* ad2w = (const float*)d_in[8];
  const float* b2   = (const float*)d_in[9];
  float* out = (float*)d_out;

  int N = in_sizes[0] / 128;   // 50000
  int E = in_sizes[1] / 2;     // 800000

  char* p = (char*)d_ws;
  size_t off = 0;
  auto alloc = [&](size_t b){ size_t c = off; off = (off + b + 255) & ~(size_t)255; return c; };
  unsigned short* h1b   = (unsigned short*)(p + alloc((size_t)N*256*2)); // 25.6 MB bf16
  unsigned short* hact_b= (unsigned short*)(p + alloc((size_t)N*256*2)); // 25.6 MB bf16
  float* h2     = (float*)(p + alloc((size_t)N*16*4));    // 3.2 MB
  float* as1    = (float*)(p + alloc((size_t)N*4*4));
  float* ad1    = (float*)(p + alloc((size_t)N*4*4));
  float* as2    = (float*)(p + alloc((size_t)N*4));
  float* ad2    = (float*)(p + alloc((size_t)N*4));
  int*   counts = (int*)(p + alloc((size_t)N*4));
  int*   beg    = (int*)(p + alloc((size_t)N*4));
  int*   cursor = (int*)(p + alloc((size_t)N*4));
  int*   adj    = (int*)(p + alloc((size_t)E*4));         // 3.2 MB
  int*   flag   = (int*)(p + alloc(4));
  int*   totalCtr = (int*)(p + alloc(4));

  hipMemsetAsync(counts, 0, (size_t)N*4, stream);
  hipMemsetAsync(totalCtr, 0, 4, stream);
  detect_kernel<<<1, 64, 0, stream>>>(ei, flag);
  count_kernel<<<2048, 256, 0, stream>>>(ei, flag, counts, E);
  assign_kernel<<<(N + 255)/256, 256, 0, stream>>>(counts, beg, cursor, totalCtr, N);
  fill_kernel<<<2048, 256, 0, stream>>>(ei, flag, cursor, adj, E);

  gemm1_mfma<<<(N + 63)/64, 256, 0, stream>>>(x, W1, as1w, ad1w, h1b, as1, ad1, N);
  agg1_kernel<<<(N*64 + 255)/256, 256, 0, stream>>>(h1b, as1, ad1, b1, beg, counts, adj, hact_b, N);
  gemm2_mfma<<<(N + 63)/64, 256, 0, stream>>>(hact_b, W2, as2w, ad2w, h2, as2, ad2, N);
  agg2_kernel<<<(N*64 + 255)/256, 256, 0, stream>>>(h2, as2, ad2, b2, beg, counts, adj, out, N);
}

// Round 7
// 254.279 us; speedup vs baseline: 1.1723x; 1.0595x over previous
//
#include <hip/hip_runtime.h>
#include <math.h>

#define NEG 0.2f

typedef __attribute__((ext_vector_type(8))) short bf16x8;
typedef __attribute__((ext_vector_type(4))) float f32x4;

__device__ __forceinline__ float lrelu(float x){ return x > 0.f ? x : NEG*x; }

__device__ __forceinline__ float bflo(unsigned u){ return __uint_as_float(u << 16); }
__device__ __forceinline__ float bfhi(unsigned u){ return __uint_as_float(u & 0xffff0000u); }

// select a0..a3 by 2-bit index encoded as booleans (bit0, bit1)
__device__ __forceinline__ float selh(float a0, float a1, float a2, float a3,
                                      bool bit0, bool bit1){
  float lo = bit0 ? a1 : a0;
  float hi = bit0 ? a3 : a2;
  return bit1 ? hi : lo;
}

__device__ __forceinline__ unsigned short f2bf(float x){
  unsigned u = __float_as_uint(x);
  u += 0x7fffu + ((u >> 16) & 1u);     // RNE
  return (unsigned short)(u >> 16);
}

// ---- detect whether edge_index is int64 (odd 32-bit words all zero) or int32 ----
__global__ void detect_kernel(const int* __restrict__ ei, int* __restrict__ flag){
  int lane = threadIdx.x;                 // 64 threads, 1 block
  int v = ei[2*lane + 1];
  unsigned long long b = __ballot(v != 0);
  if (lane == 0) flag[0] = (b == 0ULL) ? 1 : 0;   // 1 => int64 layout
}

__global__ void count_kernel(const int* __restrict__ ei, const int* __restrict__ flag,
                             int* __restrict__ counts, int E){
  int is64 = flag[0];
  int stride = gridDim.x * blockDim.x;
  for (int i = blockIdx.x*blockDim.x + threadIdx.x; i < E; i += stride){
    int d = is64 ? ei[2*(E + i)] : ei[E + i];
    atomicAdd(&counts[d], 1);
  }
}

// ---- parallel segment assignment: no ordered prefix sum needed for CSR ----
__global__ void assign_kernel(const int* __restrict__ counts, int* __restrict__ beg,
                              int* __restrict__ cursor, int* __restrict__ totalCtr, int n){
  int i = blockIdx.x*blockDim.x + threadIdx.x;
  if (i < n){
    int c = counts[i];
    int b = atomicAdd(totalCtr, c);
    beg[i] = b;
    cursor[i] = b;
  }
}

__global__ void fill_kernel(const int* __restrict__ ei, const int* __restrict__ flag,
                            int* __restrict__ cursor, int* __restrict__ adj, int E){
  int is64 = flag[0];
  int stride = gridDim.x * blockDim.x;
  for (int i = blockIdx.x*blockDim.x + threadIdx.x; i < E; i += stride){
    int s = is64 ? ei[2*i]       : ei[i];
    int d = is64 ? ei[2*(E + i)] : ei[E + i];
    int pos = atomicAdd(&cursor[d], 1);
    adj[pos] = s;
  }
}

// ---- GEMM1 via MFMA: h1b = bf16(x @ W1)  [N,128]x[128,256], fused alpha1 ----
__device__ __forceinline__ int wt_addr(int col, int k){   // address in shorts, K=128
  int g = (k >> 3) ^ (col & 7);
  return col*128 + g*8 + (k & 7);
}

__global__ __launch_bounds__(256) void gemm1_mfma(const float* __restrict__ x,
                             const float* __restrict__ W,
                             const float* __restrict__ asrcw, const float* __restrict__ adstw,
                             unsigned short* __restrict__ h1b,
                             float* __restrict__ as1, float* __restrict__ ad1, int N){
  __shared__ unsigned short wt[256*128];   // 65536 B
  int t = threadIdx.x;
  int lane = t & 63, w = t >> 6;
  int row0 = blockIdx.x * 64 + w * 16;

  // A-frags from x: row = lane&15, k = (lane>>4)*8 + j
  int arow = row0 + (lane & 15);
  if (arow >= N) arow = N - 1;
  const float* xr = x + (size_t)arow * 128 + (lane >> 4) * 8;
  bf16x8 afrag[4];
  #pragma unroll
  for (int kk = 0; kk < 4; kk++){
    float4 p0 = *reinterpret_cast<const float4*>(xr + kk*32);
    float4 p1 = *reinterpret_cast<const float4*>(xr + kk*32 + 4);
    afrag[kk][0] = (short)f2bf(p0.x); afrag[kk][1] = (short)f2bf(p0.y);
    afrag[kk][2] = (short)f2bf(p0.z); afrag[kk][3] = (short)f2bf(p0.w);
    afrag[kk][4] = (short)f2bf(p1.x); afrag[kk][5] = (short)f2bf(p1.y);
    afrag[kk][6] = (short)f2bf(p1.z); afrag[kk][7] = (short)f2bf(p1.w);
  }

  // stage W1 transposed: thread t owns col c=t; coalesced global reads
  int c = t;
  for (int k0 = 0; k0 < 128; k0 += 8){
    bf16x8 v;
    #pragma unroll
    for (int j = 0; j < 8; j++) v[j] = (short)f2bf(W[(size_t)(k0+j)*256 + c]);
    *reinterpret_cast<bf16x8*>(&wt[wt_addr(c, k0)]) = v;
  }
  __syncthreads();

  f32x4 acc[16];
  #pragma unroll
  for (int n = 0; n < 16; n++) acc[n] = (f32x4){0.f,0.f,0.f,0.f};
  #pragma unroll
  for (int kk = 0; kk < 4; kk++){
    #pragma unroll
    for (int n = 0; n < 16; n++){
      bf16x8 b = *reinterpret_cast<const bf16x8*>(
          &wt[wt_addr(n*16 + (lane & 15), kk*32 + (lane >> 4)*8)]);
      acc[n] = __builtin_amdgcn_mfma_f32_16x16x32_bf16(afrag[kk], b, acc[n], 0, 0, 0);
    }
  }

  // store h1b: row = row0 + (lane>>4)*4 + r, col = n*16 + (lane&15)
  int rbase = row0 + (lane >> 4)*4;
  int cbase = lane & 15;
  #pragma unroll
  for (int n = 0; n < 16; n++){
    #pragma unroll
    for (int r = 0; r < 4; r++){
      int row = rbase + r;
      if (row < N) h1b[(size_t)row*256 + n*16 + cbase] = f2bf(acc[n][r]);
    }
  }

  // fused alpha1
  float av[16], dv[16];
  #pragma unroll
  for (int n = 0; n < 16; n++){
    av[n] = asrcw[n*16 + cbase];
    dv[n] = adstw[n*16 + cbase];
  }
  #pragma unroll
  for (int r = 0; r < 4; r++){
    int row = rbase + r;
    float hs[4], hd[4];
    #pragma unroll
    for (int h = 0; h < 4; h++){
      float ps = 0.f, pd = 0.f;
      #pragma unroll
      for (int q = 0; q < 4; q++){
        int n = h*4 + q;
        ps = fmaf(acc[n][r], av[n], ps);
        pd = fmaf(acc[n][r], dv[n], pd);
      }
      #pragma unroll
      for (int off = 1; off < 16; off <<= 1){
        ps += __shfl_xor(ps, off, 64);
        pd += __shfl_xor(pd, off, 64);
      }
      hs[h] = ps; hd[h] = pd;
    }
    if (cbase == 0 && row < N){
      *reinterpret_cast<float4*>(as1 + (size_t)row*4) = make_float4(hs[0],hs[1],hs[2],hs[3]);
      *reinterpret_cast<float4*>(ad1 + (size_t)row*4) = make_float4(hd[0],hd[1],hd[2],hd[3]);
    }
  }
}

// ---- layer-1 aggregation: wave per dst node, NO-MAX softmax (fp32-safe by range),
//      readlane src + LDS weight broadcast, bf16 gather; fused bias+ELU; bf16 store ----
__global__ void agg1_kernel(const unsigned short* __restrict__ h1b,
                            const float* __restrict__ as1,
                            const float* __restrict__ ad1, const float* __restrict__ b1,
                            const int* __restrict__ beg, const int* __restrict__ counts,
                            const int* __restrict__ adj,
                            unsigned short* __restrict__ hact_b, int N){
  __shared__ float exlds[4][256];
  int node = (blockIdx.x*blockDim.x + threadIdx.x) >> 6;
  int lane = threadIdx.x & 63;
  int w = (threadIdx.x >> 6) & 3;
  if (node >= N) return;
  int beg_ = beg[node], end_ = beg_ + counts[node];
  int myhead = lane >> 4;
  bool b4 = (lane & 16) != 0, b5 = (lane & 32) != 0;

  float4 adv4 = *reinterpret_cast<const float4*>(ad1 + (size_t)node*4);
  float adv[4] = {adv4.x, adv4.y, adv4.z, adv4.w};
  float4 sv4 = *reinterpret_cast<const float4*>(as1 + (size_t)node*4);
  float svv[4] = {sv4.x, sv4.y, sv4.z, sv4.w};

  float es[4], sp[4];
  #pragma unroll
  for (int k = 0; k < 4; k++){
    es[k] = lrelu(svv[k] + adv[k]);   // self-loop logit
    sp[k] = 0.f;
  }
  float4 acc = make_float4(0.f, 0.f, 0.f, 0.f);

  for (int base = beg_; base < end_; base += 64){
    int i = base + lane;
    bool val = i < end_;
    int srcl = val ? adj[i] : 0;
    float4 av4 = *reinterpret_cast<const float4*>(as1 + (size_t)srcl*4);
    float e[4] = {av4.x, av4.y, av4.z, av4.w};
    float ex[4];
    #pragma unroll
    for (int k = 0; k < 4; k++){
      e[k] = val ? lrelu(e[k] + adv[k]) : -3e38f;
      ex[k] = __expf(e[k]);           // invalid lanes -> 0; logits bounded ~6 so no overflow
      sp[k] += ex[k];
    }
    *reinterpret_cast<float4*>(&exlds[w][lane*4]) = make_float4(ex[0], ex[1], ex[2], ex[3]);

    // broadcast phase: readlane src, LDS weight read (1 ds_read_b32, conflict-free)
    int cnt = end_ - base; if (cnt > 64) cnt = 64;
    #pragma unroll 2
    for (int j = 0; j < cnt; j++){
      int srcj = __builtin_amdgcn_readlane(srcl, j);
      float eh = exlds[w][j*4 + myhead];
      uint2 hv = *reinterpret_cast<const uint2*>(h1b + (size_t)srcj*256 + lane*4);
      acc.x = fmaf(eh, bflo(hv.x), acc.x);
      acc.y = fmaf(eh, bfhi(hv.x), acc.y);
      acc.z = fmaf(eh, bflo(hv.y), acc.z);
      acc.w = fmaf(eh, bfhi(hv.y), acc.w);
    }
  }

  // total denominator per head
  #pragma unroll
  for (int k = 0; k < 4; k++){
    #pragma unroll
    for (int off = 32; off; off >>= 1) sp[k] += __shfl_xor(sp[k], off, 64);
  }
  // self-loop contribution
  float exs[4];
  #pragma unroll
  for (int k = 0; k < 4; k++){
    exs[k] = __expf(es[k]);
    sp[k] += exs[k];
  }
  float ehs = selh(exs[0], exs[1], exs[2], exs[3], b4, b5);
  uint2 hv = *reinterpret_cast<const uint2*>(h1b + (size_t)node*256 + lane*4);
  acc.x = fmaf(ehs, bflo(hv.x), acc.x);
  acc.y = fmaf(ehs, bfhi(hv.x), acc.y);
  acc.z = fmaf(ehs, bflo(hv.y), acc.z);
  acc.w = fmaf(ehs, bfhi(hv.y), acc.w);

  float dh = selh(sp[0], sp[1], sp[2], sp[3], b4, b5) + 1e-16f;
  float rinv = 1.0f / dh;
  float4 bv = *reinterpret_cast<const float4*>(b1 + lane*4);
  float4 o;
  o.x = acc.x*rinv + bv.x;
  o.y = acc.y*rinv + bv.y;
  o.z = acc.z*rinv + bv.z;
  o.w = acc.w*rinv + bv.w;
  o.x = o.x > 0.f ? o.x : expm1f(o.x);
  o.y = o.y > 0.f ? o.y : expm1f(o.y);
  o.z = o.z > 0.f ? o.z : expm1f(o.z);
  o.w = o.w > 0.f ? o.w : expm1f(o.w);
  ushort4 ob;
  ob.x = f2bf(o.x); ob.y = f2bf(o.y); ob.z = f2bf(o.z); ob.w = f2bf(o.w);
  *reinterpret_cast<ushort4*>(hact_b + (size_t)node*256 + lane*4) = ob;
}

// ---- GEMM2 via MFMA: h2 = hact_b @ W2  [N,256]x[256,16], fused alpha2 ----
__device__ __forceinline__ int wt2_addr(int col, int k){  // shorts, K=256
  int g = (k >> 3) ^ (col & 7);
  return col*256 + g*8 + (k & 7);
}

__global__ __launch_bounds__(256) void gemm2_mfma(const unsigned short* __restrict__ hact_b,
                             const float* __restrict__ W2,
                             const float* __restrict__ asrc2, const float* __restrict__ adst2,
                             float* __restrict__ h2, float* __restrict__ as2,
                             float* __restrict__ ad2, int N){
  __shared__ unsigned short wt[16*256];    // 8192 B
  int t = threadIdx.x;
  int lane = t & 63, w = t >> 6;
  int row0 = blockIdx.x * 64 + w * 16;

  // stage W2^T bf16: thread t owns k=t (row of W2), writes 16 cols
  {
    float4 r0 = *reinterpret_cast<const float4*>(W2 + (size_t)t*16);
    float4 r1 = *reinterpret_cast<const float4*>(W2 + (size_t)t*16 + 4);
    float4 r2 = *reinterpret_cast<const float4*>(W2 + (size_t)t*16 + 8);
    float4 r3 = *reinterpret_cast<const float4*>(W2 + (size_t)t*16 + 12);
    float wr[16] = {r0.x,r0.y,r0.z,r0.w, r1.x,r1.y,r1.z,r1.w,
                    r2.x,r2.y,r2.z,r2.w, r3.x,r3.y,r3.z,r3.w};
    #pragma unroll
    for (int cc = 0; cc < 16; cc++) wt[wt2_addr(cc, t)] = f2bf(wr[cc]);
  }

  // A-frag source row
  int arow = row0 + (lane & 15);
  if (arow >= N) arow = N - 1;
  const unsigned short* hr = hact_b + (size_t)arow*256 + (lane >> 4)*8;
  __syncthreads();

  f32x4 acc = (f32x4){0.f,0.f,0.f,0.f};
  #pragma unroll
  for (int kk = 0; kk < 8; kk++){
    bf16x8 a = *reinterpret_cast<const bf16x8*>(hr + kk*32);
    bf16x8 b = *reinterpret_cast<const bf16x8*>(
        &wt[wt2_addr(lane & 15, kk*32 + (lane >> 4)*8)]);
    acc = __builtin_amdgcn_mfma_f32_16x16x32_bf16(a, b, acc, 0, 0, 0);
  }

  // store h2 + fused alpha2 (cols = lane&15, rows = row0 + (lane>>4)*4 + r)
  int rbase = row0 + (lane >> 4)*4;
  int cbase = lane & 15;
  float avc = asrc2[cbase], dvc = adst2[cbase];
  #pragma unroll
  for (int r = 0; r < 4; r++){
    int row = rbase + r;
    if (row < N) h2[(size_t)row*16 + cbase] = acc[r];
    float ps = acc[r]*avc, pd = acc[r]*dvc;
    #pragma unroll
    for (int off = 1; off < 16; off <<= 1){
      ps += __shfl_xor(ps, off, 64);
      pd += __shfl_xor(pd, off, 64);
    }
    if (cbase == 0 && row < N){ as2[row] = ps; ad2[row] = pd; }
  }
}

// ---- layer-2 aggregation: SINGLE PASS (no max), wave per node,
//      4 edge-groups x 16 channels, fused bias+log_softmax ----
__global__ void agg2_kernel(const float* __restrict__ h2, const float* __restrict__ as2,
                            const float* __restrict__ ad2, const float* __restrict__ b2,
                            const int* __restrict__ beg, const int* __restrict__ counts,
                            const int* __restrict__ adj,
                            float* __restrict__ out, int N){
  int node = (blockIdx.x*blockDim.x + threadIdx.x) >> 6;
  int lane = threadIdx.x & 63;
  if (node >= N) return;
  int beg_ = beg[node], end_ = beg_ + counts[node];
  float adn = ad2[node];
  float eself = lrelu(as2[node] + adn);
  int g = lane >> 4, c = lane & 15;
  float s = 0.f, acc = 0.f;
  for (int i = beg_ + g; i < end_; i += 4){
    int src = adj[i];
    float ex = __expf(lrelu(as2[src] + adn));   // logits bounded ~2 -> no overflow
    s += ex;
    acc = fmaf(ex, h2[(size_t)src*16 + c], acc);
  }
  if (g == 0){
    float ex = __expf(eself);
    s += ex;
    acc = fmaf(ex, h2[(size_t)node*16 + c], acc);
  }
  acc += __shfl_xor(acc, 16, 64); acc += __shfl_xor(acc, 32, 64);
  s   += __shfl_xor(s,   16, 64); s   += __shfl_xor(s,   32, 64);
  float v = acc / (s + 1e-16f) + b2[c];
  float mx = v;
  #pragma unroll
  for (int off = 1; off < 16; off <<= 1) mx = fmaxf(mx, __shfl_xor(mx, off, 64));
  float se = expf(v - mx);
  #pragma unroll
  for (int off = 1; off < 16; off <<= 1) se += __shfl_xor(se, off, 64);
  float o = v - mx - logf(se);
  if (lane < 16) out[(size_t)node*16 + c] = o;
}

extern "C" void kernel_launch(void* const* d_in, const int* in_sizes, int n_in,
                              void* d_out, int out_size, void* d_ws, size_t ws_size,
                              hipStream_t stream){
  const float* x    = (const float*)d_in[0];
  const int*   ei   = (const int*)d_in[1];
  const float* W1   = (const float*)d_in[2];
  const float* as1w = (const float*)d_in[3];
  const float* ad1w = (const float*)d_in[4];
  const float* b1   = (const float*)d_in[5];
  const float* W2   = (const float*)d_in[6];
  const float* as2w = (const float*)d_in[7];
  const float* ad2w = (const float*)d_in[8];
  const float* b2   = (const float*)d_in[9];
  float* out = (float*)d_out;

  int N = in_sizes[0] / 128;   // 50000
  int E = in_sizes[1] / 2;     // 800000

  char* p = (char*)d_ws;
  size_t off = 0;
  auto alloc = [&](size_t b){ size_t c = off; off = (off + b + 255) & ~(size_t)255; return c; };
  unsigned short* h1b   = (unsigned short*)(p + alloc((size_t)N*256*2)); // 25.6 MB bf16
  unsigned short* hact_b= (unsigned short*)(p + alloc((size_t)N*256*2)); // 25.6 MB bf16
  float* h2     = (float*)(p + alloc((size_t)N*16*4));    // 3.2 MB
  float* as1    = (float*)(p + alloc((size_t)N*4*4));
  float* ad1    = (float*)(p + alloc((size_t)N*4*4));
  float* as2    = (float*)(p + alloc((size_t)N*4));
  float* ad2    = (float*)(p + alloc((size_t)N*4));
  int*   counts = (int*)(p + alloc((size_t)N*4));
  int*   beg    = (int*)(p + alloc((size_t)N*4));
  int*   cursor = (int*)(p + alloc((size_t)N*4));
  int*   adj    = (int*)(p + alloc((size_t)E*4));         // 3.2 MB
  int*   flag   = (int*)(p + alloc(4));
  int*   totalCtr = (int*)(p + alloc(4));

  hipMemsetAsync(counts, 0, (size_t)N*4, stream);
  hipMemsetAsync(totalCtr, 0, 4, stream);
  detect_kernel<<<1, 64, 0, stream>>>(ei, flag);
  count_kernel<<<2048, 256, 0, stream>>>(ei, flag, counts, E);
  assign_kernel<<<(N + 255)/256, 256, 0, stream>>>(counts, beg, cursor, totalCtr, N);
  fill_kernel<<<2048, 256, 0, stream>>>(ei, flag, cursor, adj, E);

  gemm1_mfma<<<(N + 63)/64, 256, 0, stream>>>(x, W1, as1w, ad1w, h1b, as1, ad1, N);
  agg1_kernel<<<(N*64 + 255)/256, 256, 0, stream>>>(h1b, as1, ad1, b1, beg, counts, adj, hact_b, N);
  gemm2_mfma<<<(N + 63)/64, 256, 0, stream>>>(hact_b, W2, as2w, ad2w, h2, as2, ad2, N);
  agg2_kernel<<<(N*64 + 255)/256, 256, 0, stream>>>(h2, as2, ad2, b2, beg, counts, adj, out, N);
}

// Round 8
// 243.274 us; speedup vs baseline: 1.2253x; 1.0452x over previous
//
#include <hip/hip_runtime.h>
#include <math.h>

#define NEG 0.2f

typedef __attribute__((ext_vector_type(8))) short bf16x8;
typedef __attribute__((ext_vector_type(4))) float f32x4;

__device__ __forceinline__ float lrelu(float x){ return x > 0.f ? x : NEG*x; }

__device__ __forceinline__ float bflo(unsigned u){ return __uint_as_float(u << 16); }
__device__ __forceinline__ float bfhi(unsigned u){ return __uint_as_float(u & 0xffff0000u); }

// select a0..a3 by 2-bit index encoded as booleans (bit0, bit1)
__device__ __forceinline__ float selh(float a0, float a1, float a2, float a3,
                                      bool bit0, bool bit1){
  float lo = bit0 ? a1 : a0;
  float hi = bit0 ? a3 : a2;
  return bit1 ? hi : lo;
}

__device__ __forceinline__ unsigned short f2bf(float x){
  unsigned u = __float_as_uint(x);
  u += 0x7fffu + ((u >> 16) & 1u);     // RNE
  return (unsigned short)(u >> 16);
}

// ---- detect whether edge_index is int64 (odd 32-bit words all zero) or int32 ----
__global__ void detect_kernel(const int* __restrict__ ei, int* __restrict__ flag){
  int lane = threadIdx.x;                 // 64 threads, 1 block
  int v = ei[2*lane + 1];
  unsigned long long b = __ballot(v != 0);
  if (lane == 0) flag[0] = (b == 0ULL) ? 1 : 0;   // 1 => int64 layout
}

__global__ void count_kernel(const int* __restrict__ ei, const int* __restrict__ flag,
                             int* __restrict__ counts, int E){
  int is64 = flag[0];
  int stride = gridDim.x * blockDim.x;
  for (int i = blockIdx.x*blockDim.x + threadIdx.x; i < E; i += stride){
    int d = is64 ? ei[2*(E + i)] : ei[E + i];
    atomicAdd(&counts[d], 1);
  }
}

// ---- parallel segment assignment: no ordered prefix sum needed for CSR ----
__global__ void assign_kernel(const int* __restrict__ counts, int* __restrict__ beg,
                              int* __restrict__ cursor, int* __restrict__ totalCtr, int n){
  int i = blockIdx.x*blockDim.x + threadIdx.x;
  if (i < n){
    int c = counts[i];
    int b = atomicAdd(totalCtr, c);
    beg[i] = b;
    cursor[i] = b;
  }
}

__global__ void fill_kernel(const int* __restrict__ ei, const int* __restrict__ flag,
                            int* __restrict__ cursor, int* __restrict__ adj, int E){
  int is64 = flag[0];
  int stride = gridDim.x * blockDim.x;
  for (int i = blockIdx.x*blockDim.x + threadIdx.x; i < E; i += stride){
    int s = is64 ? ei[2*i]       : ei[i];
    int d = is64 ? ei[2*(E + i)] : ei[E + i];
    int pos = atomicAdd(&cursor[d], 1);
    adj[pos] = s;
  }
}

// ---- GEMM1 via MFMA: h1b = bf16(x @ W1)  [N,128]x[128,256], fused alpha1 ----
__device__ __forceinline__ int wt_addr(int col, int k){   // address in shorts, K=128
  int g = (k >> 3) ^ (col & 7);
  return col*128 + g*8 + (k & 7);
}

__global__ __launch_bounds__(256) void gemm1_mfma(const float* __restrict__ x,
                             const float* __restrict__ W,
                             const float* __restrict__ asrcw, const float* __restrict__ adstw,
                             unsigned short* __restrict__ h1b,
                             float* __restrict__ as1, float* __restrict__ ad1, int N){
  __shared__ unsigned short wt[256*128];   // 65536 B
  int t = threadIdx.x;
  int lane = t & 63, w = t >> 6;
  int row0 = blockIdx.x * 64 + w * 16;

  // A-frags from x: row = lane&15, k = (lane>>4)*8 + j
  int arow = row0 + (lane & 15);
  if (arow >= N) arow = N - 1;
  const float* xr = x + (size_t)arow * 128 + (lane >> 4) * 8;
  bf16x8 afrag[4];
  #pragma unroll
  for (int kk = 0; kk < 4; kk++){
    float4 p0 = *reinterpret_cast<const float4*>(xr + kk*32);
    float4 p1 = *reinterpret_cast<const float4*>(xr + kk*32 + 4);
    afrag[kk][0] = (short)f2bf(p0.x); afrag[kk][1] = (short)f2bf(p0.y);
    afrag[kk][2] = (short)f2bf(p0.z); afrag[kk][3] = (short)f2bf(p0.w);
    afrag[kk][4] = (short)f2bf(p1.x); afrag[kk][5] = (short)f2bf(p1.y);
    afrag[kk][6] = (short)f2bf(p1.z); afrag[kk][7] = (short)f2bf(p1.w);
  }

  // stage W1 transposed: thread t owns col c=t; coalesced global reads
  int c = t;
  for (int k0 = 0; k0 < 128; k0 += 8){
    bf16x8 v;
    #pragma unroll
    for (int j = 0; j < 8; j++) v[j] = (short)f2bf(W[(size_t)(k0+j)*256 + c]);
    *reinterpret_cast<bf16x8*>(&wt[wt_addr(c, k0)]) = v;
  }
  __syncthreads();

  f32x4 acc[16];
  #pragma unroll
  for (int n = 0; n < 16; n++) acc[n] = (f32x4){0.f,0.f,0.f,0.f};
  #pragma unroll
  for (int kk = 0; kk < 4; kk++){
    #pragma unroll
    for (int n = 0; n < 16; n++){
      bf16x8 b = *reinterpret_cast<const bf16x8*>(
          &wt[wt_addr(n*16 + (lane & 15), kk*32 + (lane >> 4)*8)]);
      acc[n] = __builtin_amdgcn_mfma_f32_16x16x32_bf16(afrag[kk], b, acc[n], 0, 0, 0);
    }
  }

  // store h1b: row = row0 + (lane>>4)*4 + r, col = n*16 + (lane&15)
  int rbase = row0 + (lane >> 4)*4;
  int cbase = lane & 15;
  #pragma unroll
  for (int n = 0; n < 16; n++){
    #pragma unroll
    for (int r = 0; r < 4; r++){
      int row = rbase + r;
      if (row < N) h1b[(size_t)row*256 + n*16 + cbase] = f2bf(acc[n][r]);
    }
  }

  // fused alpha1
  float av[16], dv[16];
  #pragma unroll
  for (int n = 0; n < 16; n++){
    av[n] = asrcw[n*16 + cbase];
    dv[n] = adstw[n*16 + cbase];
  }
  #pragma unroll
  for (int r = 0; r < 4; r++){
    int row = rbase + r;
    float hs[4], hd[4];
    #pragma unroll
    for (int h = 0; h < 4; h++){
      float ps = 0.f, pd = 0.f;
      #pragma unroll
      for (int q = 0; q < 4; q++){
        int n = h*4 + q;
        ps = fmaf(acc[n][r], av[n], ps);
        pd = fmaf(acc[n][r], dv[n], pd);
      }
      #pragma unroll
      for (int off = 1; off < 16; off <<= 1){
        ps += __shfl_xor(ps, off, 64);
        pd += __shfl_xor(pd, off, 64);
      }
      hs[h] = ps; hd[h] = pd;
    }
    if (cbase == 0 && row < N){
      *reinterpret_cast<float4*>(as1 + (size_t)row*4) = make_float4(hs[0],hs[1],hs[2],hs[3]);
      *reinterpret_cast<float4*>(ad1 + (size_t)row*4) = make_float4(hd[0],hd[1],hd[2],hd[3]);
    }
  }
}

// ---- layer-1 aggregation: wave per dst node, no-max softmax, 4-edge batched
//      gather (4 rows in flight), LDS weight broadcast; fused bias+ELU; bf16 store ----
__global__ void agg1_kernel(const unsigned short* __restrict__ h1b,
                            const float* __restrict__ as1,
                            const float* __restrict__ ad1, const float* __restrict__ b1,
                            const int* __restrict__ beg, const int* __restrict__ counts,
                            const int* __restrict__ adj,
                            unsigned short* __restrict__ hact_b, int N){
  __shared__ float exlds[4][256];
  int node = (blockIdx.x*blockDim.x + threadIdx.x) >> 6;
  int lane = threadIdx.x & 63;
  int w = (threadIdx.x >> 6) & 3;
  if (node >= N) return;
  int beg_ = beg[node], end_ = beg_ + counts[node];
  int myhead = lane >> 4;
  bool b4 = (lane & 16) != 0, b5 = (lane & 32) != 0;

  float4 adv4 = *reinterpret_cast<const float4*>(ad1 + (size_t)node*4);
  float adv[4] = {adv4.x, adv4.y, adv4.z, adv4.w};
  float4 sv4 = *reinterpret_cast<const float4*>(as1 + (size_t)node*4);
  float svv[4] = {sv4.x, sv4.y, sv4.z, sv4.w};

  float es[4], sp[4];
  #pragma unroll
  for (int k = 0; k < 4; k++){
    es[k] = lrelu(svv[k] + adv[k]);   // self-loop logit
    sp[k] = 0.f;
  }
  float4 acc = make_float4(0.f, 0.f, 0.f, 0.f);
  const float* exw = &exlds[w][0];
  unsigned loff = lane * 4;            // element offset of this lane's 8-byte slice

  for (int base = beg_; base < end_; base += 64){
    int i = base + lane;
    bool val = i < end_;
    int srcl = val ? adj[i] : 0;
    float4 av4 = *reinterpret_cast<const float4*>(as1 + (size_t)srcl*4);
    float e[4] = {av4.x, av4.y, av4.z, av4.w};
    float ex[4];
    #pragma unroll
    for (int k = 0; k < 4; k++){
      e[k] = val ? lrelu(e[k] + adv[k]) : -3e38f;
      ex[k] = __expf(e[k]);           // invalid lanes -> 0; logits bounded ~6
      sp[k] += ex[k];
    }
    *reinterpret_cast<float4*>(&exlds[w][lane*4]) = make_float4(ex[0], ex[1], ex[2], ex[3]);

    int cnt = end_ - base; if (cnt > 64) cnt = 64;
    int j = 0;
    // 4 edges per iteration: 4 independent 8B gathers in flight
    for (; j + 4 <= cnt; j += 4){
      int s0 = __builtin_amdgcn_readlane(srcl, j);
      int s1 = __builtin_amdgcn_readlane(srcl, j+1);
      int s2 = __builtin_amdgcn_readlane(srcl, j+2);
      int s3 = __builtin_amdgcn_readlane(srcl, j+3);
      uint2 h0 = *reinterpret_cast<const uint2*>(h1b + (size_t)s0*256 + loff);
      uint2 h1 = *reinterpret_cast<const uint2*>(h1b + (size_t)s1*256 + loff);
      uint2 h2 = *reinterpret_cast<const uint2*>(h1b + (size_t)s2*256 + loff);
      uint2 h3 = *reinterpret_cast<const uint2*>(h1b + (size_t)s3*256 + loff);
      float e0 = exw[(j+0)*4 + myhead];
      float e1 = exw[(j+1)*4 + myhead];
      float e2 = exw[(j+2)*4 + myhead];
      float e3 = exw[(j+3)*4 + myhead];
      acc.x = fmaf(e0, bflo(h0.x), acc.x);
      acc.y = fmaf(e0, bfhi(h0.x), acc.y);
      acc.z = fmaf(e0, bflo(h0.y), acc.z);
      acc.w = fmaf(e0, bfhi(h0.y), acc.w);
      acc.x = fmaf(e1, bflo(h1.x), acc.x);
      acc.y = fmaf(e1, bfhi(h1.x), acc.y);
      acc.z = fmaf(e1, bflo(h1.y), acc.z);
      acc.w = fmaf(e1, bfhi(h1.y), acc.w);
      acc.x = fmaf(e2, bflo(h2.x), acc.x);
      acc.y = fmaf(e2, bfhi(h2.x), acc.y);
      acc.z = fmaf(e2, bflo(h2.y), acc.z);
      acc.w = fmaf(e2, bfhi(h2.y), acc.w);
      acc.x = fmaf(e3, bflo(h3.x), acc.x);
      acc.y = fmaf(e3, bfhi(h3.x), acc.y);
      acc.z = fmaf(e3, bflo(h3.y), acc.z);
      acc.w = fmaf(e3, bfhi(h3.y), acc.w);
    }
    for (; j < cnt; j++){
      int sj = __builtin_amdgcn_readlane(srcl, j);
      uint2 hv = *reinterpret_cast<const uint2*>(h1b + (size_t)sj*256 + loff);
      float eh = exw[j*4 + myhead];
      acc.x = fmaf(eh, bflo(hv.x), acc.x);
      acc.y = fmaf(eh, bfhi(hv.x), acc.y);
      acc.z = fmaf(eh, bflo(hv.y), acc.z);
      acc.w = fmaf(eh, bfhi(hv.y), acc.w);
    }
  }

  // total denominator per head
  #pragma unroll
  for (int k = 0; k < 4; k++){
    #pragma unroll
    for (int off = 32; off; off >>= 1) sp[k] += __shfl_xor(sp[k], off, 64);
  }
  // self-loop contribution
  float exs[4];
  #pragma unroll
  for (int k = 0; k < 4; k++){
    exs[k] = __expf(es[k]);
    sp[k] += exs[k];
  }
  float ehs = selh(exs[0], exs[1], exs[2], exs[3], b4, b5);
  uint2 hv = *reinterpret_cast<const uint2*>(h1b + (size_t)node*256 + loff);
  acc.x = fmaf(ehs, bflo(hv.x), acc.x);
  acc.y = fmaf(ehs, bfhi(hv.x), acc.y);
  acc.z = fmaf(ehs, bflo(hv.y), acc.z);
  acc.w = fmaf(ehs, bfhi(hv.y), acc.w);

  float dh = selh(sp[0], sp[1], sp[2], sp[3], b4, b5) + 1e-16f;
  float rinv = 1.0f / dh;
  float4 bv = *reinterpret_cast<const float4*>(b1 + lane*4);
  float4 o;
  o.x = acc.x*rinv + bv.x;
  o.y = acc.y*rinv + bv.y;
  o.z = acc.z*rinv + bv.z;
  o.w = acc.w*rinv + bv.w;
  o.x = o.x > 0.f ? o.x : expm1f(o.x);
  o.y = o.y > 0.f ? o.y : expm1f(o.y);
  o.z = o.z > 0.f ? o.z : expm1f(o.z);
  o.w = o.w > 0.f ? o.w : expm1f(o.w);
  ushort4 ob;
  ob.x = f2bf(o.x); ob.y = f2bf(o.y); ob.z = f2bf(o.z); ob.w = f2bf(o.w);
  *reinterpret_cast<ushort4*>(hact_b + (size_t)node*256 + loff) = ob;
}

// ---- GEMM2 via MFMA: h2 = hact_b @ W2  [N,256]x[256,16], fused alpha2 ----
__device__ __forceinline__ int wt2_addr(int col, int k){  // shorts, K=256
  int g = (k >> 3) ^ (col & 7);
  return col*256 + g*8 + (k & 7);
}

__global__ __launch_bounds__(256) void gemm2_mfma(const unsigned short* __restrict__ hact_b,
                             const float* __restrict__ W2,
                             const float* __restrict__ asrc2, const float* __restrict__ adst2,
                             float* __restrict__ h2, float* __restrict__ as2,
                             float* __restrict__ ad2, int N){
  __shared__ unsigned short wt[16*256];    // 8192 B
  int t = threadIdx.x;
  int lane = t & 63, w = t >> 6;
  int row0 = blockIdx.x * 64 + w * 16;

  // stage W2^T bf16: thread t owns k=t (row of W2), writes 16 cols
  {
    float4 r0 = *reinterpret_cast<const float4*>(W2 + (size_t)t*16);
    float4 r1 = *reinterpret_cast<const float4*>(W2 + (size_t)t*16 + 4);
    float4 r2 = *reinterpret_cast<const float4*>(W2 + (size_t)t*16 + 8);
    float4 r3 = *reinterpret_cast<const float4*>(W2 + (size_t)t*16 + 12);
    float wr[16] = {r0.x,r0.y,r0.z,r0.w, r1.x,r1.y,r1.z,r1.w,
                    r2.x,r2.y,r2.z,r2.w, r3.x,r3.y,r3.z,r3.w};
    #pragma unroll
    for (int cc = 0; cc < 16; cc++) wt[wt2_addr(cc, t)] = f2bf(wr[cc]);
  }

  // A-frag source row
  int arow = row0 + (lane & 15);
  if (arow >= N) arow = N - 1;
  const unsigned short* hr = hact_b + (size_t)arow*256 + (lane >> 4)*8;
  __syncthreads();

  f32x4 acc = (f32x4){0.f,0.f,0.f,0.f};
  #pragma unroll
  for (int kk = 0; kk < 8; kk++){
    bf16x8 a = *reinterpret_cast<const bf16x8*>(hr + kk*32);
    bf16x8 b = *reinterpret_cast<const bf16x8*>(
        &wt[wt2_addr(lane & 15, kk*32 + (lane >> 4)*8)]);
    acc = __builtin_amdgcn_mfma_f32_16x16x32_bf16(a, b, acc, 0, 0, 0);
  }

  // store h2 + fused alpha2 (cols = lane&15, rows = row0 + (lane>>4)*4 + r)
  int rbase = row0 + (lane >> 4)*4;
  int cbase = lane & 15;
  float avc = asrc2[cbase], dvc = adst2[cbase];
  #pragma unroll
  for (int r = 0; r < 4; r++){
    int row = rbase + r;
    if (row < N) h2[(size_t)row*16 + cbase] = acc[r];
    float ps = acc[r]*avc, pd = acc[r]*dvc;
    #pragma unroll
    for (int off = 1; off < 16; off <<= 1){
      ps += __shfl_xor(ps, off, 64);
      pd += __shfl_xor(pd, off, 64);
    }
    if (cbase == 0 && row < N){ as2[row] = ps; ad2[row] = pd; }
  }
}

// ---- layer-2 aggregation: SINGLE PASS (no max), wave per node,
//      4 edge-groups x 16 channels, fused bias+log_softmax ----
__global__ void agg2_kernel(const float* __restrict__ h2, const float* __restrict__ as2,
                            const float* __restrict__ ad2, const float* __restrict__ b2,
                            const int* __restrict__ beg, const int* __restrict__ counts,
                            const int* __restrict__ adj,
                            float* __restrict__ out, int N){
  int node = (blockIdx.x*blockDim.x + threadIdx.x) >> 6;
  int lane = threadIdx.x & 63;
  if (node >= N) return;
  int beg_ = beg[node], end_ = beg_ + counts[node];
  float adn = ad2[node];
  float eself = lrelu(as2[node] + adn);
  int g = lane >> 4, c = lane & 15;
  float s = 0.f, acc = 0.f;
  for (int i = beg_ + g; i < end_; i += 4){
    int src = adj[i];
    float ex = __expf(lrelu(as2[src] + adn));   // logits bounded ~2 -> no overflow
    s += ex;
    acc = fmaf(ex, h2[(size_t)src*16 + c], acc);
  }
  if (g == 0){
    float ex = __expf(eself);
    s += ex;
    acc = fmaf(ex, h2[(size_t)node*16 + c], acc);
  }
  acc += __shfl_xor(acc, 16, 64); acc += __shfl_xor(acc, 32, 64);
  s   += __shfl_xor(s,   16, 64); s   += __shfl_xor(s,   32, 64);
  float v = acc / (s + 1e-16f) + b2[c];
  float mx = v;
  #pragma unroll
  for (int off = 1; off < 16; off <<= 1) mx = fmaxf(mx, __shfl_xor(mx, off, 64));
  float se = expf(v - mx);
  #pragma unroll
  for (int off = 1; off < 16; off <<= 1) se += __shfl_xor(se, off, 64);
  float o = v - mx - logf(se);
  if (lane < 16) out[(size_t)node*16 + c] = o;
}

extern "C" void kernel_launch(void* const* d_in, const int* in_sizes, int n_in,
                              void* d_out, int out_size, void* d_ws, size_t ws_size,
                              hipStream_t stream){
  const float* x    = (const float*)d_in[0];
  const int*   ei   = (const int*)d_in[1];
  const float* W1   = (const float*)d_in[2];
  const float* as1w = (const float*)d_in[3];
  const float* ad1w = (const float*)d_in[4];
  const float* b1   = (const float*)d_in[5];
  const float* W2   = (const float*)d_in[6];
  const float* as2w = (const float*)d_in[7];
  const float* ad2w = (const float*)d_in[8];
  const float* b2   = (const float*)d_in[9];
  float* out = (float*)d_out;

  int N = in_sizes[0] / 128;   // 50000
  int E = in_sizes[1] / 2;     // 800000

  char* p = (char*)d_ws;
  size_t off = 0;
  auto alloc = [&](size_t b){ size_t c = off; off = (off + b + 255) & ~(size_t)255; return c; };
  unsigned short* h1b   = (unsigned short*)(p + alloc((size_t)N*256*2)); // 25.6 MB bf16
  unsigned short* hact_b= (unsigned short*)(p + alloc((size_t)N*256*2)); // 25.6 MB bf16
  float* h2     = (float*)(p + alloc((size_t)N*16*4));    // 3.2 MB
  float* as1    = (float*)(p + alloc((size_t)N*4*4));
  float* ad1    = (float*)(p + alloc((size_t)N*4*4));
  float* as2    = (float*)(p + alloc((size_t)N*4));
  float* ad2    = (float*)(p + alloc((size_t)N*4));
  int*   counts = (int*)(p + alloc((size_t)N*4));
  int*   beg    = (int*)(p + alloc((size_t)N*4));
  int*   cursor = (int*)(p + alloc((size_t)N*4));
  int*   adj    = (int*)(p + alloc((size_t)E*4));         // 3.2 MB
  int*   flag   = (int*)(p + alloc(4));
  int*   totalCtr = (int*)(p + alloc(4));

  hipMemsetAsync(counts, 0, (size_t)N*4, stream);
  hipMemsetAsync(totalCtr, 0, 4, stream);
  detect_kernel<<<1, 64, 0, stream>>>(ei, flag);
  count_kernel<<<2048, 256, 0, stream>>>(ei, flag, counts, E);
  assign_kernel<<<(N + 255)/256, 256, 0, stream>>>(counts, beg, cursor, totalCtr, N);
  fill_kernel<<<2048, 256, 0, stream>>>(ei, flag, cursor, adj, E);

  gemm1_mfma<<<(N + 63)/64, 256, 0, stream>>>(x, W1, as1w, ad1w, h1b, as1, ad1, N);
  agg1_kernel<<<(N*64 + 255)/256, 256, 0, stream>>>(h1b, as1, ad1, b1, beg, counts, adj, hact_b, N);
  gemm2_mfma<<<(N + 63)/64, 256, 0, stream>>>(hact_b, W2, as2w, ad2w, h2, as2, ad2, N);
  agg2_kernel<<<(N*64 + 255)/256, 256, 0, stream>>>(h2, as2, ad2, b2, beg, counts, adj, out, N);
}